// Round 1
// baseline (351.204 us; speedup 1.0000x reference)
//
#include <hip/hip_runtime.h>
#include <stdint.h>

#define M_TOK 256
#define K_IN  4096
#define N_OUT 11008
#define K_EXT 4160              // 4096 + 16 lora + 48 zero pad
#define ROWB  (K_EXT * 2)       // bytes per x_ext row = 8320
#define BN    64
#define NBLK  172               // 11008 / 64
#define STEPS 65                // 64 qweight steps + 1 lora tail step

typedef __attribute__((ext_vector_type(8))) short s16x8;
typedef __attribute__((ext_vector_type(8))) unsigned short u16x8;
typedef __attribute__((ext_vector_type(4))) float f32x4;

__device__ __forceinline__ unsigned short f2bf(float f) {
  union { float f; unsigned int u; } v; v.f = f;
  unsigned int u = v.u;
  u += 0x7fffu + ((u >> 16) & 1u);   // round-to-nearest-even
  return (unsigned short)(u >> 16);
}

// ---------------- prep 1: x fp32 -> bf16 (row stride K_EXT) ----------------
__global__ __launch_bounds__(512) void convert_x_kernel(
    const float* __restrict__ x, unsigned short* __restrict__ xe)
{
  const int t  = blockIdx.x * 512 + threadIdx.x;   // 131072 threads
  const int e0 = t * 8;                            // 8 floats each
  const int m  = e0 >> 12;
  const int k  = e0 & 4095;
  const float4 f0 = *(const float4*)(x + e0);
  const float4 f1 = *(const float4*)(x + e0 + 4);
  u16x8 o;
  o[0] = f2bf(f0.x); o[1] = f2bf(f0.y); o[2] = f2bf(f0.z); o[3] = f2bf(f0.w);
  o[4] = f2bf(f1.x); o[5] = f2bf(f1.y); o[6] = f2bf(f1.z); o[7] = f2bf(f1.w);
  *(u16x8*)(xe + (size_t)m * K_EXT + k) = o;
}

// ------- prep 2: t2[m,r] = 2 * sum_k x[m,k]*A[r,k] -> x_ext cols 4096.. -------
__global__ __launch_bounds__(256) void lora_t_kernel(
    const float* __restrict__ x, const float* __restrict__ la,
    unsigned short* __restrict__ xe)
{
  const int m   = blockIdx.x;
  const int tid = threadIdx.x;
  float acc[16];
  #pragma unroll
  for (int r = 0; r < 16; ++r) acc[r] = 0.f;
  for (int it = 0; it < 16; ++it) {
    const int k = it * 256 + tid;
    const float xv = x[(size_t)m * K_IN + k];
    #pragma unroll
    for (int r = 0; r < 16; ++r) acc[r] += xv * la[r * K_IN + k];
  }
  #pragma unroll
  for (int r = 0; r < 16; ++r) {
    #pragma unroll
    for (int off = 32; off > 0; off >>= 1) acc[r] += __shfl_down(acc[r], off);
  }
  __shared__ float red[4][16];
  const int wave = tid >> 6, lane = tid & 63;
  if (lane == 0) {
    #pragma unroll
    for (int r = 0; r < 16; ++r) red[wave][r] = acc[r];
  }
  __syncthreads();
  if (tid < 16) {
    const float s = red[0][tid] + red[1][tid] + red[2][tid] + red[3][tid];
    xe[(size_t)m * K_EXT + K_IN + tid] = f2bf(2.0f * s);   // SCALING folded here
  } else if (tid < 64) {
    xe[(size_t)m * K_EXT + K_IN + tid] = 0;                // zero pad (ws is poisoned!)
  }
}

// ---------------- main: 256 x 11008 GEMM, dequant-on-the-fly ----------------
__global__ __launch_bounds__(512, 4) void gptq_lora_gemm(
    const int* __restrict__ qw, const float* __restrict__ sc,
    const int* __restrict__ zr, const float* __restrict__ lb,
    const unsigned short* __restrict__ xe, float* __restrict__ out)
{
  __shared__ unsigned short xs[M_TOK * 64];   // 32 KB, XOR-swizzled rows
  __shared__ unsigned short wt[BN * 64];      // 8 KB,  XOR-swizzled rows

  const int tid  = threadIdx.x;
  const int wave = tid >> 6;
  const int lane = tid & 63;
  const int n0   = blockIdx.x * BN;

  const int wm = wave >> 1;   // 0..3  (64 rows each)
  const int wn = wave & 1;    // 0..1  (32 cols each)

  // W-staging assignment: row snl (0..63), 8 ints starting at sko
  const int snl    = tid >> 3;
  const int sko    = (tid & 7) * 8;
  const int nglob  = n0 + snl;
  const int wt_off = snl * 128 + ((sko * 2) ^ ((snl & 7) << 4));

  f32x4 acc[4][2];
  #pragma unroll
  for (int i = 0; i < 4; ++i)
    #pragma unroll
    for (int j = 0; j < 2; ++j) acc[i][j] = (f32x4)0.f;

  const int arow_lo = lane & 15;
  const int kb_hi   = (lane >> 4) * 16;   // byte offset inside 128B row slice

  #pragma unroll 1
  for (int step = 0; step < STEPS; ++step) {
    const int k0 = step * 64;
    __syncthreads();

    // ---- stage x tile: linear LDS dest, inverse-swizzled global source ----
    {
      const char* xb = (const char*)xe;
      #pragma unroll
      for (int i = 0; i < 4; ++i) {
        const int base = (wave * 32 + i * 8) * 128;   // wave-uniform LDS byte base
        const int o    = base + lane * 16;
        const int mrow = o >> 7;
        const int kb   = o & 127;
        const char* src = xb + (size_t)mrow * ROWB + k0 * 2 + (kb ^ ((mrow & 7) << 4));
        __builtin_amdgcn_global_load_lds(
            (const __attribute__((address_space(1))) void*)src,
            (__attribute__((address_space(3))) void*)((char*)xs + base),
            16, 0, 0);
      }
    }

    // ---- stage W tile: load int4s, dequant, pack bf16, swizzled ds_write ----
    {
      unsigned short wv[8];
      if (step < 64) {
        const int g   = k0 >> 7;                    // 64 | 128 -> one group per step
        const float s = sc[nglob * 32 + g];
        const float z = (float)zr[nglob * 32 + g];
        const int4 q0 = *(const int4*)(qw + (size_t)nglob * K_IN + k0 + sko);
        const int4 q1 = *(const int4*)(qw + (size_t)nglob * K_IN + k0 + sko + 4);
        wv[0] = f2bf(((float)q0.x - z) * s);
        wv[1] = f2bf(((float)q0.y - z) * s);
        wv[2] = f2bf(((float)q0.z - z) * s);
        wv[3] = f2bf(((float)q0.w - z) * s);
        wv[4] = f2bf(((float)q1.x - z) * s);
        wv[5] = f2bf(((float)q1.y - z) * s);
        wv[6] = f2bf(((float)q1.z - z) * s);
        wv[7] = f2bf(((float)q1.w - z) * s);
      } else {
        // lora tail: W_ext[n][4096+r] = B[n][r] for r<16, else 0
        #pragma unroll
        for (int j = 0; j < 8; ++j) {
          const int kl = sko + j;
          wv[j] = (kl < 16) ? f2bf(lb[nglob * 16 + kl]) : (unsigned short)0;
        }
      }
      int4 pk;
      pk.x = (int)wv[0] | ((int)wv[1] << 16);
      pk.y = (int)wv[2] | ((int)wv[3] << 16);
      pk.z = (int)wv[4] | ((int)wv[5] << 16);
      pk.w = (int)wv[6] | ((int)wv[7] << 16);
      *(int4*)((char*)wt + wt_off) = pk;
    }

    __syncthreads();

    // ---- compute: 16 MFMA per wave per step ----
    {
      s16x8 bfr[2][2];
      #pragma unroll
      for (int nf = 0; nf < 2; ++nf) {
        const int c   = wn * 32 + nf * 16 + arow_lo;
        const int swz = (c & 7) << 4;
        #pragma unroll
        for (int ks = 0; ks < 2; ++ks) {
          const int off = c * 128 + ((ks * 64 + kb_hi) ^ swz);
          bfr[nf][ks] = *(const s16x8*)((const char*)wt + off);
        }
      }
      #pragma unroll
      for (int mf = 0; mf < 4; ++mf) {
        const int r   = wm * 64 + mf * 16 + arow_lo;
        const int swz = (r & 7) << 4;
        s16x8 af[2];
        #pragma unroll
        for (int ks = 0; ks < 2; ++ks) {
          const int off = r * 128 + ((ks * 64 + kb_hi) ^ swz);
          af[ks] = *(const s16x8*)((const char*)xs + off);
        }
        #pragma unroll
        for (int nf = 0; nf < 2; ++nf) {
          acc[mf][nf] = __builtin_amdgcn_mfma_f32_16x16x32_bf16(af[0], bfr[nf][0], acc[mf][nf], 0, 0, 0);
          acc[mf][nf] = __builtin_amdgcn_mfma_f32_16x16x32_bf16(af[1], bfr[nf][1], acc[mf][nf], 0, 0, 0);
        }
      }
    }
  }

  // ---- epilogue: C/D layout col=lane&15, row=(lane>>4)*4+reg ----
  const int rb = wm * 64 + (lane >> 4) * 4;
  const int cb = n0 + wn * 32 + (lane & 15);
  #pragma unroll
  for (int mf = 0; mf < 4; ++mf) {
    #pragma unroll
    for (int nf = 0; nf < 2; ++nf) {
      #pragma unroll
      for (int j = 0; j < 4; ++j) {
        out[(size_t)(rb + mf * 16 + j) * N_OUT + (cb + nf * 16)] = acc[mf][nf][j];
      }
    }
  }
}

extern "C" void kernel_launch(void* const* d_in, const int* in_sizes, int n_in,
                              void* d_out, int out_size, void* d_ws, size_t ws_size,
                              hipStream_t stream) {
  const float* x  = (const float*)d_in[0];
  const int*   qw = (const int*)d_in[1];
  const float* sc = (const float*)d_in[2];
  const int*   zr = (const int*)d_in[3];
  const float* la = (const float*)d_in[4];
  const float* lb = (const float*)d_in[5];
  float* out = (float*)d_out;
  unsigned short* xe = (unsigned short*)d_ws;   // 256*4160*2 = 2.03 MB

  convert_x_kernel<<<256, 512, 0, stream>>>(x, xe);
  lora_t_kernel<<<256, 256, 0, stream>>>(x, la, xe);
  gptq_lora_gemm<<<NBLK, 512, 0, stream>>>(qw, sc, zr, lb, xe, out);
}

// Round 2
// 327.142 us; speedup vs baseline: 1.0736x; 1.0736x over previous
//
#include <hip/hip_runtime.h>
#include <stdint.h>

#define M_TOK 256
#define K_IN  4096
#define N_OUT 11008
#define K_EXT 4160              // 4096 + 16 lora + 48 zero pad
#define ROWB  (K_EXT * 2)       // bytes per x_ext row = 8320
#define BM    128
#define BN    64
#define NBLK  172               // 11008 / 64
#define STEPS 65                // 64 qweight steps + 1 lora tail step

typedef __attribute__((ext_vector_type(8))) short s16x8;
typedef __attribute__((ext_vector_type(8))) unsigned short u16x8;
typedef __attribute__((ext_vector_type(4))) float f32x4;

__device__ __forceinline__ unsigned short f2bf(float f) {
  union { float f; unsigned int u; } v; v.f = f;
  unsigned int u = v.u;
  u += 0x7fffu + ((u >> 16) & 1u);   // round-to-nearest-even
  return (unsigned short)(u >> 16);
}

// ---- prep: x fp32 -> bf16 row (stride K_EXT) + lora t2 appended as cols 4096.. ----
// one block per token row m
__global__ __launch_bounds__(512) void prep_kernel(
    const float* __restrict__ x, const float* __restrict__ la,
    unsigned short* __restrict__ xe)
{
  const int m   = blockIdx.x;
  const int tid = threadIdx.x;         // 512 threads, 8 floats each
  const int k   = tid * 8;
  const float* xr = x + (size_t)m * K_IN;
  const float4 f0 = *(const float4*)(xr + k);
  const float4 f1 = *(const float4*)(xr + k + 4);
  u16x8 o;
  o[0] = f2bf(f0.x); o[1] = f2bf(f0.y); o[2] = f2bf(f0.z); o[3] = f2bf(f0.w);
  o[4] = f2bf(f1.x); o[5] = f2bf(f1.y); o[6] = f2bf(f1.z); o[7] = f2bf(f1.w);
  *(u16x8*)(xe + (size_t)m * K_EXT + k) = o;

  // lora partial dot: acc[r] = sum over this thread's 8 k of x*A[r]
  float acc[16];
  #pragma unroll
  for (int r = 0; r < 16; ++r) {
    const float4 a0 = *(const float4*)(la + r * K_IN + k);
    const float4 a1 = *(const float4*)(la + r * K_IN + k + 4);
    acc[r] = f0.x * a0.x + f0.y * a0.y + f0.z * a0.z + f0.w * a0.w
           + f1.x * a1.x + f1.y * a1.y + f1.z * a1.z + f1.w * a1.w;
  }
  #pragma unroll
  for (int r = 0; r < 16; ++r) {
    #pragma unroll
    for (int off = 32; off > 0; off >>= 1) acc[r] += __shfl_down(acc[r], off);
  }
  __shared__ float red[8][16];
  const int wave = tid >> 6, lane = tid & 63;
  if (lane == 0) {
    #pragma unroll
    for (int r = 0; r < 16; ++r) red[wave][r] = acc[r];
  }
  __syncthreads();
  if (tid < 16) {
    float s = 0.f;
    #pragma unroll
    for (int w = 0; w < 8; ++w) s += red[w][tid];
    xe[(size_t)m * K_EXT + K_IN + tid] = f2bf(2.0f * s);   // SCALING folded
  } else if (tid < 64) {
    xe[(size_t)m * K_EXT + K_IN + tid] = 0;                // zero pad (ws poisoned)
  }
}

// ---------------- main: 256 x 11008 GEMM, dequant-on-the-fly ----------------
// BM=128 x BN=64, BK=64, 256 threads (4 waves: 2M x 2N), double-buffered 2-phase.
__global__ __launch_bounds__(256, 3) void gptq_lora_gemm(
    const int* __restrict__ qw, const float* __restrict__ sc,
    const int* __restrict__ zr, const float* __restrict__ lb,
    const unsigned short* __restrict__ xe, float* __restrict__ out)
{
  __shared__ unsigned short xs[2][BM * 64];   // 2 x 16 KB, XOR-swizzled rows
  __shared__ unsigned short wt[2][BN * 64];   // 2 x  8 KB, XOR-swizzled rows

  const int tid  = threadIdx.x;
  const int wave = tid >> 6;      // 0..3
  const int lane = tid & 63;
  const int n0   = blockIdx.x * BN;
  const int m0   = blockIdx.y * BM;

  const int wm = wave >> 1;       // 0..1 : 64 rows
  const int wn = wave & 1;        // 0..1 : 32 cols

  // W-staging: row = tid>>2 (0..63), 16 ints starting at (tid&3)*16
  const int srow  = tid >> 2;
  const int sko   = (tid & 3) * 16;
  const int nglob = n0 + srow;
  const size_t qrow = (size_t)nglob * K_IN;
  const int swz_s   = (srow & 7) << 4;
  const int wt_off0 = srow * 128 + ((sko * 2) ^ swz_s);
  const int wt_off1 = srow * 128 + ((sko * 2 + 16) ^ swz_s);

  f32x4 acc[4][2];
  #pragma unroll
  for (int i = 0; i < 4; ++i)
    #pragma unroll
    for (int j = 0; j < 2; ++j) acc[i][j] = (f32x4)0.f;

  const int arow_lo = lane & 15;
  const int kb_hi   = (lane >> 4) * 16;

  const char* xb = (const char*)xe;

  // ---- helpers ----
  auto stage_x = [&](int buf, int step) {
    const int k0 = step * 64;
    #pragma unroll
    for (int i = 0; i < 4; ++i) {
      const int base = (wave * 32 + i * 8) * 128;          // wave-uniform LDS byte base
      const int o    = base + lane * 16;
      const int mrow = o >> 7;
      const int kb   = o & 127;
      const char* src = xb + (size_t)(m0 + mrow) * ROWB + k0 * 2 + (kb ^ ((mrow & 7) << 4));
      __builtin_amdgcn_global_load_lds(
          (const __attribute__((address_space(1))) void*)src,
          (__attribute__((address_space(3))) void*)((char*)xs[buf] + base),
          16, 0, 0);
    }
  };

  auto load_q = [&](int step, int4 q[4], float& s, float& z) {
    if (step < 64) {
      const int k0 = step * 64;
      const int g  = k0 >> 7;
      s = sc[nglob * 32 + g];
      z = (float)zr[nglob * 32 + g];
      const int* p = qw + qrow + k0 + sko;
      q[0] = *(const int4*)(p);
      q[1] = *(const int4*)(p + 4);
      q[2] = *(const int4*)(p + 8);
      q[3] = *(const int4*)(p + 12);
    } else if (sko == 0) {
      // lora tail: bitcast 16 floats of B row
      const int4* p = (const int4*)(lb + (size_t)nglob * 16);
      q[0] = p[0]; q[1] = p[1]; q[2] = p[2]; q[3] = p[3];
    }
  };

  auto dequant_write = [&](int step, const int4 q[4], float s, float z, int buf) {
    unsigned short wv[16];
    if (step < 64) {
      #pragma unroll
      for (int i = 0; i < 4; ++i) {
        wv[i * 4 + 0] = f2bf(((float)q[i].x - z) * s);
        wv[i * 4 + 1] = f2bf(((float)q[i].y - z) * s);
        wv[i * 4 + 2] = f2bf(((float)q[i].z - z) * s);
        wv[i * 4 + 3] = f2bf(((float)q[i].w - z) * s);
      }
    } else {
      #pragma unroll
      for (int i = 0; i < 4; ++i) {
        wv[i * 4 + 0] = (sko == 0) ? f2bf(__int_as_float(q[i].x)) : (unsigned short)0;
        wv[i * 4 + 1] = (sko == 0) ? f2bf(__int_as_float(q[i].y)) : (unsigned short)0;
        wv[i * 4 + 2] = (sko == 0) ? f2bf(__int_as_float(q[i].z)) : (unsigned short)0;
        wv[i * 4 + 3] = (sko == 0) ? f2bf(__int_as_float(q[i].w)) : (unsigned short)0;
      }
    }
    int4 pk0, pk1;
    pk0.x = (int)wv[0]  | ((int)wv[1]  << 16);
    pk0.y = (int)wv[2]  | ((int)wv[3]  << 16);
    pk0.z = (int)wv[4]  | ((int)wv[5]  << 16);
    pk0.w = (int)wv[6]  | ((int)wv[7]  << 16);
    pk1.x = (int)wv[8]  | ((int)wv[9]  << 16);
    pk1.y = (int)wv[10] | ((int)wv[11] << 16);
    pk1.z = (int)wv[12] | ((int)wv[13] << 16);
    pk1.w = (int)wv[14] | ((int)wv[15] << 16);
    *(int4*)((char*)wt[buf] + wt_off0) = pk0;
    *(int4*)((char*)wt[buf] + wt_off1) = pk1;
  };

  auto compute = [&](int buf) {
    s16x8 bfr[2][2];
    #pragma unroll
    for (int nf = 0; nf < 2; ++nf) {
      const int c   = wn * 32 + nf * 16 + arow_lo;
      const int swz = (c & 7) << 4;
      #pragma unroll
      for (int ks = 0; ks < 2; ++ks) {
        const int off = c * 128 + ((ks * 64 + kb_hi) ^ swz);
        bfr[nf][ks] = *(const s16x8*)((const char*)wt[buf] + off);
      }
    }
    #pragma unroll
    for (int mf = 0; mf < 4; ++mf) {
      const int r   = wm * 64 + mf * 16 + arow_lo;
      const int swz = (r & 7) << 4;
      s16x8 af[2];
      #pragma unroll
      for (int ks = 0; ks < 2; ++ks) {
        const int off = r * 128 + ((ks * 64 + kb_hi) ^ swz);
        af[ks] = *(const s16x8*)((const char*)xs[buf] + off);
      }
      #pragma unroll
      for (int nf = 0; nf < 2; ++nf) {
        acc[mf][nf] = __builtin_amdgcn_mfma_f32_16x16x32_bf16(af[0], bfr[nf][0], acc[mf][nf], 0, 0, 0);
        acc[mf][nf] = __builtin_amdgcn_mfma_f32_16x16x32_bf16(af[1], bfr[nf][1], acc[mf][nf], 0, 0, 0);
      }
    }
  };

  // ---- prologue: fill buf 0 for step 0 ----
  {
    int4 q[4]; float s, z;
    load_q(0, q, s, z);
    stage_x(0, 0);
    dequant_write(0, q, s, z, 0);
  }
  __syncthreads();

  // ---- 2-phase pipelined main loop ----
  int buf = 0;
  #pragma unroll 1
  for (int t = 0; t < STEPS; ++t) {
    const bool more = (t + 1 < STEPS);
    int4 qn[4]; float sn = 0.f, zn = 0.f;
    if (more) {
      load_q(t + 1, qn, sn, zn);     // global -> regs, no wait
      stage_x(buf ^ 1, t + 1);       // global -> LDS (async)
    }
    compute(buf);                    // MFMA on current buffer
    if (more) dequant_write(t + 1, qn, sn, zn, buf ^ 1);
    __syncthreads();                 // drains vmcnt (x-lds) + lgkm (ds_write)
    buf ^= 1;
  }

  // ---- epilogue: C/D layout col=lane&15, row=(lane>>4)*4+reg ----
  const int rb = m0 + wm * 64 + (lane >> 4) * 4;
  const int cb = n0 + wn * 32 + (lane & 15);
  #pragma unroll
  for (int mf = 0; mf < 4; ++mf) {
    #pragma unroll
    for (int nf = 0; nf < 2; ++nf) {
      #pragma unroll
      for (int j = 0; j < 4; ++j) {
        out[(size_t)(rb + mf * 16 + j) * N_OUT + (cb + nf * 16)] = acc[mf][nf][j];
      }
    }
  }
}

extern "C" void kernel_launch(void* const* d_in, const int* in_sizes, int n_in,
                              void* d_out, int out_size, void* d_ws, size_t ws_size,
                              hipStream_t stream) {
  const float* x  = (const float*)d_in[0];
  const int*   qw = (const int*)d_in[1];
  const float* sc = (const float*)d_in[2];
  const int*   zr = (const int*)d_in[3];
  const float* la = (const float*)d_in[4];
  const float* lb = (const float*)d_in[5];
  float* out = (float*)d_out;
  unsigned short* xe = (unsigned short*)d_ws;   // 256*4160*2 = 2.03 MB

  prep_kernel<<<M_TOK, 512, 0, stream>>>(x, la, xe);
  gptq_lora_gemm<<<dim3(NBLK, 2), 256, 0, stream>>>(qw, sc, zr, lb, xe, out);
}